// Round 1
// baseline (393.197 us; speedup 1.0000x reference)
//
#include <hip/hip_runtime.h>

#define NN 100000
#define NE 1600000
#define NH 64
#define NG 64

static constexpr int TPB = 256;

// ---- edge pass 1: deg[dst] += w ----
__global__ void k_edge_deg(const int* __restrict__ dst, const float* __restrict__ w,
                           float* __restrict__ deg) {
    int gid = blockIdx.x * blockDim.x + threadIdx.x;
    int T = gridDim.x * blockDim.x;
    for (int e = gid; e < NE; e += T)
        atomicAdd(&deg[dst[e]], w[e]);
}

// ---- node pass: dinv = rsqrt(deg+1) (self loop weight 1); agg1 = dinv^2 * x (self-loop msg) ----
__global__ void k_node_dinv(const float* __restrict__ x, float* __restrict__ deg,
                            float* __restrict__ agg1, float* __restrict__ scal) {
    int gid = blockIdx.x * blockDim.x + threadIdx.x;
    int T = gridDim.x * blockDim.x;
    for (int n = gid; n < NN; n += T) {
        float d = deg[n] + 1.0f;           // deg always > 0 (self loop)
        float di = rsqrtf(d);
        deg[n] = di;                        // in-place: deg -> dinv
        agg1[n] = di * di * x[n];
    }
    if (gid == 0) { scal[0] = 0.f; scal[1] = 0.f; }
}

// ---- edge pass 2: agg1[dst] += dinv[src]*w*dinv[dst] * x[src] ----
__global__ void k_edge_agg1(const int* __restrict__ src, const int* __restrict__ dst,
                            const float* __restrict__ w, const float* __restrict__ dinv,
                            const float* __restrict__ x, float* __restrict__ agg1) {
    int gid = blockIdx.x * blockDim.x + threadIdx.x;
    int T = gridDim.x * blockDim.x;
    for (int e = gid; e < NE; e += T) {
        int s = src[e], d = dst[e];
        float nrm = dinv[s] * w[e] * dinv[d];
        atomicAdd(&agg1[d], nrm * x[s]);
    }
}

// ---- reduce: sum and sumsq of agg1 ----
__global__ void k_reduce(const float* __restrict__ agg1, float* __restrict__ scal) {
    float s = 0.f, q = 0.f;
    int gid = blockIdx.x * blockDim.x + threadIdx.x;
    int T = gridDim.x * blockDim.x;
    for (int n = gid; n < NN; n += T) {
        float a = agg1[n];
        s += a; q += a * a;
    }
    for (int off = 32; off > 0; off >>= 1) {
        s += __shfl_down(s, off);
        q += __shfl_down(q, off);
    }
    __shared__ float red[2][4];
    int wave = threadIdx.x >> 6, lane = threadIdx.x & 63;
    if (lane == 0) { red[0][wave] = s; red[1][wave] = q; }
    __syncthreads();
    if (threadIdx.x == 0) {
        float ss = red[0][0] + red[0][1] + red[0][2] + red[0][3];
        float qq = red[1][0] + red[1][1] + red[1][2] + red[1][3];
        atomicAdd(&scal[0], ss);
        atomicAdd(&scal[1], qq);
    }
}

// ---- tiny prep: c[j] = W1[j]*gamma[j]*rsqrt(var*W1[j]^2 + eps); zero pool accumulators ----
__global__ void k_prep(float* __restrict__ scal, const float* __restrict__ W1,
                       const float* __restrict__ gamma, float* __restrict__ c,
                       float* __restrict__ pooled, float* __restrict__ cnt) {
    int j = threadIdx.x;   // 64 threads
    float mu  = scal[0] * (1.0f / NN);
    float var = scal[1] * (1.0f / NN) - mu * mu;
    float w1 = W1[j];
    c[j] = w1 * gamma[j] * rsqrtf(var * w1 * w1 + 1e-5f);
    pooled[2 * j] = 0.f; pooled[2 * j + 1] = 0.f; cnt[j] = 0.f;
    if (j == 0) scal[2] = mu;
}

// ---- node pass: hp[n][k] = sum_j relu((agg1-mu)*c[j] + beta[j]) * W2[j][k]; seed agg2 w/ self loop ----
__global__ void k_node_hp(const float* __restrict__ agg1, const float* __restrict__ dinv,
                          const float* __restrict__ c, const float* __restrict__ beta,
                          const float* __restrict__ W2, const float* __restrict__ scal,
                          float* __restrict__ hp, float* __restrict__ agg2) {
    __shared__ float sc[NH], sb[NH], s0[NH], s1[NH];
    if (threadIdx.x < NH) {
        int j = threadIdx.x;
        sc[j] = c[j]; sb[j] = beta[j]; s0[j] = W2[2 * j]; s1[j] = W2[2 * j + 1];
    }
    __syncthreads();
    float mu = scal[2];
    int gid = blockIdx.x * blockDim.x + threadIdx.x;
    int T = gridDim.x * blockDim.x;
    for (int n = gid; n < NN; n += T) {
        float a = agg1[n] - mu;
        float h0 = 0.f, h1 = 0.f;
#pragma unroll
        for (int j = 0; j < NH; ++j) {
            float t = fmaxf(fmaf(a, sc[j], sb[j]), 0.f);
            h0 = fmaf(t, s0[j], h0);
            h1 = fmaf(t, s1[j], h1);
        }
        hp[2 * n] = h0; hp[2 * n + 1] = h1;
        float di = dinv[n];
        float sl = di * di;
        agg2[2 * n] = sl * h0; agg2[2 * n + 1] = sl * h1;
    }
}

// ---- edge pass 3: agg2[dst][k] += norm * hp[src][k] ----
__global__ void k_edge_agg2(const int* __restrict__ src, const int* __restrict__ dst,
                            const float* __restrict__ w, const float* __restrict__ dinv,
                            const float* __restrict__ hp, float* __restrict__ agg2) {
    int gid = blockIdx.x * blockDim.x + threadIdx.x;
    int T = gridDim.x * blockDim.x;
    for (int e = gid; e < NE; e += T) {
        int s = src[e], d = dst[e];
        float nrm = dinv[s] * w[e] * dinv[d];
        float2 h = *reinterpret_cast<const float2*>(hp + 2 * s);
        atomicAdd(&agg2[2 * d],     nrm * h.x);
        atomicAdd(&agg2[2 * d + 1], nrm * h.y);
    }
}

// ---- pool: per-graph sums (batch sorted -> wave-uniform fast path) ----
__global__ void k_pool(const float* __restrict__ agg2, const int* __restrict__ batch,
                       float* __restrict__ pooled, float* __restrict__ cnt) {
    __shared__ float ls0[NG], ls1[NG], lc[NG];
    if (threadIdx.x < NG) { ls0[threadIdx.x] = 0.f; ls1[threadIdx.x] = 0.f; lc[threadIdx.x] = 0.f; }
    __syncthreads();
    int gid = blockIdx.x * blockDim.x + threadIdx.x;
    int T = gridDim.x * blockDim.x;
    int lane = threadIdx.x & 63;
    for (int n = gid; __any(n < NN); n += T) {
        bool valid = n < NN;
        int b = 0;
        float vx = 0.f, vy = 0.f;
        if (valid) {
            b = batch[n];
            float2 v = *reinterpret_cast<const float2*>(agg2 + 2 * n);
            vx = v.x; vy = v.y;
        }
        int b0 = __shfl(b, 0);   // lane 0 has the smallest n -> valid whenever any lane is
        bool uni = __all(valid ? (b == b0) : 1);
        if (uni) {
            float rc = valid ? 1.f : 0.f;
            for (int off = 32; off > 0; off >>= 1) {
                vx += __shfl_down(vx, off);
                vy += __shfl_down(vy, off);
                rc += __shfl_down(rc, off);
            }
            if (lane == 0) {
                atomicAdd(&ls0[b0], vx); atomicAdd(&ls1[b0], vy); atomicAdd(&lc[b0], rc);
            }
        } else if (valid) {
            atomicAdd(&ls0[b], vx); atomicAdd(&ls1[b], vy); atomicAdd(&lc[b], 1.f);
        }
    }
    __syncthreads();
    if (threadIdx.x < NG) {
        int g = threadIdx.x;
        atomicAdd(&pooled[2 * g],     ls0[g]);
        atomicAdd(&pooled[2 * g + 1], ls1[g]);
        atomicAdd(&cnt[g],            lc[g]);
    }
}

// ---- finalize: out = pooled/max(cnt,1) + b2 (b2 only when cnt>0, matching segment mean) ----
__global__ void k_final(const float* __restrict__ pooled, const float* __restrict__ cnt,
                        const float* __restrict__ b2, float* __restrict__ out) {
    int i = threadIdx.x;   // 128 threads
    if (i < 2 * NG) {
        int g = i >> 1, k = i & 1;
        float cg = cnt[g];
        out[i] = pooled[i] / fmaxf(cg, 1.0f) + (cg > 0.f ? b2[k] : 0.f);
    }
}

extern "C" void kernel_launch(void* const* d_in, const int* in_sizes, int n_in,
                              void* d_out, int out_size, void* d_ws, size_t ws_size,
                              hipStream_t stream) {
    const float* x     = (const float*)d_in[0];
    const int*   ei    = (const int*)  d_in[1];
    const float* ew    = (const float*)d_in[2];
    const int*   batch = (const int*)  d_in[3];
    const float* W1    = (const float*)d_in[4];
    // d_in[5] = b1: cancels exactly in batch-norm; unused
    const float* gamma = (const float*)d_in[6];
    const float* beta  = (const float*)d_in[7];
    const float* W2    = (const float*)d_in[8];
    const float* b2    = (const float*)d_in[9];
    float* out = (float*)d_out;

    float* ws     = (float*)d_ws;
    float* deg    = ws;                 // [NN]  -> becomes dinv in-place
    float* agg1   = ws + NN;            // [NN]
    float* hp     = ws + 2 * NN;        // [NN*2]
    float* agg2   = ws + 4 * NN;        // [NN*2]
    float* scal   = ws + 6 * NN;        // [3]  sum, sumsq, mu
    float* c      = ws + 6 * NN + 8;    // [64]
    float* pooled = ws + 6 * NN + 80;   // [128]
    float* cnt    = ws + 6 * NN + 224;  // [64]

    const int* srcp = ei;
    const int* dstp = ei + NE;

    const int ebl = 2048;                       // edge kernels, grid-stride
    const int nbl = (NN + TPB - 1) / TPB;       // node kernels

    hipMemsetAsync(deg, 0, NN * sizeof(float), stream);
    k_edge_deg <<<ebl, TPB, 0, stream>>>(dstp, ew, deg);
    k_node_dinv<<<nbl, TPB, 0, stream>>>(x, deg, agg1, scal);
    k_edge_agg1<<<ebl, TPB, 0, stream>>>(srcp, dstp, ew, deg, x, agg1);
    k_reduce   <<<256, TPB, 0, stream>>>(agg1, scal);
    k_prep     <<<1,   64,  0, stream>>>(scal, W1, gamma, c, pooled, cnt);
    k_node_hp  <<<nbl, TPB, 0, stream>>>(agg1, deg, c, beta, W2, scal, hp, agg2);
    k_edge_agg2<<<ebl, TPB, 0, stream>>>(srcp, dstp, ew, deg, hp, agg2);
    k_pool     <<<128, TPB, 0, stream>>>(agg2, batch, pooled, cnt);
    k_final    <<<1,   128, 0, stream>>>(pooled, cnt, b2, out);
}

// Round 2
// 219.792 us; speedup vs baseline: 1.7889x; 1.7889x over previous
//
#include <hip/hip_runtime.h>

#define NN 100000
#define NE 1600000
#define NH 64
#define NG 64

#define RNG1 8192   // range width for scalar gather passes (deg, t1)
#define R1   13     // ceil(NN/RNG1)
#define RNG2 4096   // range width for 2-wide gather pass (t2)
#define R2   25     // ceil(NN/RNG2)

static constexpr int TPB  = 256;   // node kernels
static constexpr int ETPB = 512;   // edge-stream kernels

// ================= gather path =================

// pass A1: partial_deg[c][n] = sum of w over edges in chunk c with dst==n (n in range r)
__global__ void kA_deg(const int* __restrict__ dst, const float* __restrict__ w,
                       float* __restrict__ partial, int C) {
    __shared__ float bins[RNG1];
    int r = blockIdx.x / C, c = blockIdx.x % C;
    int base = r * RNG1;
    for (int i = threadIdx.x; i < RNG1; i += blockDim.x) bins[i] = 0.f;
    __syncthreads();
    long e0 = ((long)c * NE / C) & ~3L;
    long e1 = (c == C - 1) ? NE : (((long)(c + 1) * NE / C) & ~3L);
    for (long e = e0 + (long)threadIdx.x * 4; e < e1; e += (long)blockDim.x * 4) {
        int4 d4 = *reinterpret_cast<const int4*>(dst + e);
        int ds[4] = {d4.x, d4.y, d4.z, d4.w};
#pragma unroll
        for (int k = 0; k < 4; ++k) {
            unsigned off = (unsigned)(ds[k] - base);
            if (off < (unsigned)RNG1) atomicAdd(&bins[off], w[e + k]);
        }
    }
    __syncthreads();
    int len = min(RNG1, NN - base);
    for (int i = threadIdx.x; i < len; i += blockDim.x)
        partial[(size_t)c * NN + base + i] = bins[i];
}

// reduce deg partials -> dinv = rsqrt(deg+1); g1 = dinv*x; zero BN accumulators
__global__ void k_reduce_deg(const float* __restrict__ partial, const float* __restrict__ x,
                             float* __restrict__ dinv, float* __restrict__ g1,
                             float* __restrict__ scal, int C) {
    int n = blockIdx.x * blockDim.x + threadIdx.x;
    if (n < NN) {
        float s = 0.f;
        for (int c = 0; c < C; ++c) s += partial[(size_t)c * NN + n];
        float di = rsqrtf(s + 1.0f);
        dinv[n] = di;
        g1[n] = di * x[n];
    }
    if (blockIdx.x == 0 && threadIdx.x == 0) { scal[0] = 0.f; scal[1] = 0.f; }
}

// pass A2: partial_t1[c][n] = sum of w * g1[src] over edges with dst==n
__global__ void kA_t1(const int* __restrict__ src, const int* __restrict__ dst,
                      const float* __restrict__ w, const float* __restrict__ g1,
                      float* __restrict__ partial, int C) {
    __shared__ float bins[RNG1];
    int r = blockIdx.x / C, c = blockIdx.x % C;
    int base = r * RNG1;
    for (int i = threadIdx.x; i < RNG1; i += blockDim.x) bins[i] = 0.f;
    __syncthreads();
    long e0 = ((long)c * NE / C) & ~3L;
    long e1 = (c == C - 1) ? NE : (((long)(c + 1) * NE / C) & ~3L);
    for (long e = e0 + (long)threadIdx.x * 4; e < e1; e += (long)blockDim.x * 4) {
        int4 d4 = *reinterpret_cast<const int4*>(dst + e);
        int ds[4] = {d4.x, d4.y, d4.z, d4.w};
#pragma unroll
        for (int k = 0; k < 4; ++k) {
            unsigned off = (unsigned)(ds[k] - base);
            if (off < (unsigned)RNG1) {
                int s = src[e + k];
                atomicAdd(&bins[off], w[e + k] * g1[s]);
            }
        }
    }
    __syncthreads();
    int len = min(RNG1, NN - base);
    for (int i = threadIdx.x; i < len; i += blockDim.x)
        partial[(size_t)c * NN + base + i] = bins[i];
}

// reduce t1 partials -> agg1 = dinv*(t1 + g1); accumulate BN sum/sumsq
__global__ void k_reduce_t1(const float* __restrict__ partial, const float* __restrict__ dinv,
                            const float* __restrict__ g1, float* __restrict__ agg1,
                            float* __restrict__ scal, int C) {
    int n = blockIdx.x * blockDim.x + threadIdx.x;
    float a = 0.f;
    if (n < NN) {
        float t = 0.f;
        for (int c = 0; c < C; ++c) t += partial[(size_t)c * NN + n];
        a = dinv[n] * (t + g1[n]);
        agg1[n] = a;
    }
    float s = a, q = a * a;
    for (int off = 32; off > 0; off >>= 1) {
        s += __shfl_down(s, off);
        q += __shfl_down(q, off);
    }
    __shared__ float red[2][4];
    int wave = threadIdx.x >> 6, lane = threadIdx.x & 63;
    if (lane == 0) { red[0][wave] = s; red[1][wave] = q; }
    __syncthreads();
    if (threadIdx.x == 0) {
        atomicAdd(&scal[0], red[0][0] + red[0][1] + red[0][2] + red[0][3]);
        atomicAdd(&scal[1], red[1][0] + red[1][1] + red[1][2] + red[1][3]);
    }
}

// tiny prep: c[j] = W1[j]*gamma[j]*rsqrt(var*W1[j]^2+eps); zero pool accumulators
__global__ void k_prep(float* __restrict__ scal, const float* __restrict__ W1,
                       const float* __restrict__ gamma, float* __restrict__ c,
                       float* __restrict__ pooled, float* __restrict__ cnt) {
    int j = threadIdx.x;   // 64 threads
    float mu  = scal[0] * (1.0f / NN);
    float var = scal[1] * (1.0f / NN) - mu * mu;
    float w1 = W1[j];
    c[j] = w1 * gamma[j] * rsqrtf(var * w1 * w1 + 1e-5f);
    pooled[2 * j] = 0.f; pooled[2 * j + 1] = 0.f; cnt[j] = 0.f;
    if (j == 0) scal[2] = mu;
}

// node pass: hp[n][k] = sum_j relu((agg1-mu)*c[j]+beta[j]) * W2[j][k]; g2 = dinv*hp
__global__ void k_node_hp(const float* __restrict__ agg1, const float* __restrict__ dinv,
                          const float* __restrict__ c, const float* __restrict__ beta,
                          const float* __restrict__ W2, const float* __restrict__ scal,
                          float* __restrict__ hp, float* __restrict__ g2) {
    __shared__ float sc[NH], sb[NH], s0[NH], s1[NH];
    if (threadIdx.x < NH) {
        int j = threadIdx.x;
        sc[j] = c[j]; sb[j] = beta[j]; s0[j] = W2[2 * j]; s1[j] = W2[2 * j + 1];
    }
    __syncthreads();
    float mu = scal[2];
    int n = blockIdx.x * blockDim.x + threadIdx.x;
    if (n < NN) {
        float a = agg1[n] - mu;
        float h0 = 0.f, h1 = 0.f;
#pragma unroll
        for (int j = 0; j < NH; ++j) {
            float t = fmaxf(fmaf(a, sc[j], sb[j]), 0.f);
            h0 = fmaf(t, s0[j], h0);
            h1 = fmaf(t, s1[j], h1);
        }
        hp[2 * n] = h0; hp[2 * n + 1] = h1;
        float di = dinv[n];
        g2[2 * n] = di * h0; g2[2 * n + 1] = di * h1;
    }
}

// pass A3: partial_t2[c][k][n] = sum of w * g2[src][k] over edges with dst==n
__global__ void kA_t2(const int* __restrict__ src, const int* __restrict__ dst,
                      const float* __restrict__ w, const float* __restrict__ g2,
                      float* __restrict__ partial, int C) {
    __shared__ float binx[RNG2], biny[RNG2];
    int r = blockIdx.x / C, c = blockIdx.x % C;
    int base = r * RNG2;
    for (int i = threadIdx.x; i < RNG2; i += blockDim.x) { binx[i] = 0.f; biny[i] = 0.f; }
    __syncthreads();
    long e0 = ((long)c * NE / C) & ~3L;
    long e1 = (c == C - 1) ? NE : (((long)(c + 1) * NE / C) & ~3L);
    for (long e = e0 + (long)threadIdx.x * 4; e < e1; e += (long)blockDim.x * 4) {
        int4 d4 = *reinterpret_cast<const int4*>(dst + e);
        int ds[4] = {d4.x, d4.y, d4.z, d4.w};
#pragma unroll
        for (int k = 0; k < 4; ++k) {
            unsigned off = (unsigned)(ds[k] - base);
            if (off < (unsigned)RNG2) {
                int s = src[e + k];
                float ww = w[e + k];
                float2 g = *reinterpret_cast<const float2*>(g2 + 2 * s);
                atomicAdd(&binx[off], ww * g.x);
                atomicAdd(&biny[off], ww * g.y);
            }
        }
    }
    __syncthreads();
    int len = min(RNG2, NN - base);
    for (int i = threadIdx.x; i < len; i += blockDim.x) {
        partial[((size_t)(2 * c)     ) * NN + base + i] = binx[i];
        partial[((size_t)(2 * c + 1) ) * NN + base + i] = biny[i];
    }
}

// reduce t2 partials -> agg2 = dinv*(t2 + g2)
__global__ void k_reduce_t2(const float* __restrict__ partial, const float* __restrict__ dinv,
                            const float* __restrict__ g2, float* __restrict__ agg2, int C) {
    int n = blockIdx.x * blockDim.x + threadIdx.x;
    if (n < NN) {
        float tx = 0.f, ty = 0.f;
        for (int c = 0; c < C; ++c) {
            tx += partial[((size_t)(2 * c))     * NN + n];
            ty += partial[((size_t)(2 * c + 1)) * NN + n];
        }
        float di = dinv[n];
        agg2[2 * n]     = di * (tx + g2[2 * n]);
        agg2[2 * n + 1] = di * (ty + g2[2 * n + 1]);
    }
}

// ================= fallback (atomic) path, used only if scratch is tiny =================

__global__ void k_edge_deg_fb(const int* __restrict__ dst, const float* __restrict__ w,
                              float* __restrict__ deg) {
    int gid = blockIdx.x * blockDim.x + threadIdx.x;
    int T = gridDim.x * blockDim.x;
    for (int e = gid; e < NE; e += T) atomicAdd(&deg[dst[e]], w[e]);
}

__global__ void k_node_dinv_fb(const float* __restrict__ x, float* __restrict__ deg,
                               float* __restrict__ agg1, float* __restrict__ scal) {
    int gid = blockIdx.x * blockDim.x + threadIdx.x;
    int T = gridDim.x * blockDim.x;
    for (int n = gid; n < NN; n += T) {
        float di = rsqrtf(deg[n] + 1.0f);
        deg[n] = di;
        agg1[n] = di * di * x[n];
    }
    if (gid == 0) { scal[0] = 0.f; scal[1] = 0.f; }
}

__global__ void k_edge_agg1_fb(const int* __restrict__ src, const int* __restrict__ dst,
                               const float* __restrict__ w, const float* __restrict__ dinv,
                               const float* __restrict__ x, float* __restrict__ agg1) {
    int gid = blockIdx.x * blockDim.x + threadIdx.x;
    int T = gridDim.x * blockDim.x;
    for (int e = gid; e < NE; e += T) {
        int s = src[e], d = dst[e];
        atomicAdd(&agg1[d], dinv[s] * w[e] * dinv[d] * x[s]);
    }
}

__global__ void k_reduce_fb(const float* __restrict__ agg1, float* __restrict__ scal) {
    float s = 0.f, q = 0.f;
    int gid = blockIdx.x * blockDim.x + threadIdx.x;
    int T = gridDim.x * blockDim.x;
    for (int n = gid; n < NN; n += T) { float a = agg1[n]; s += a; q += a * a; }
    for (int off = 32; off > 0; off >>= 1) { s += __shfl_down(s, off); q += __shfl_down(q, off); }
    __shared__ float red[2][4];
    int wave = threadIdx.x >> 6, lane = threadIdx.x & 63;
    if (lane == 0) { red[0][wave] = s; red[1][wave] = q; }
    __syncthreads();
    if (threadIdx.x == 0) {
        atomicAdd(&scal[0], red[0][0] + red[0][1] + red[0][2] + red[0][3]);
        atomicAdd(&scal[1], red[1][0] + red[1][1] + red[1][2] + red[1][3]);
    }
}

__global__ void k_node_hp_fb(const float* __restrict__ agg1, const float* __restrict__ dinv,
                             const float* __restrict__ c, const float* __restrict__ beta,
                             const float* __restrict__ W2, const float* __restrict__ scal,
                             float* __restrict__ hp, float* __restrict__ agg2) {
    __shared__ float sc[NH], sb[NH], s0[NH], s1[NH];
    if (threadIdx.x < NH) {
        int j = threadIdx.x;
        sc[j] = c[j]; sb[j] = beta[j]; s0[j] = W2[2 * j]; s1[j] = W2[2 * j + 1];
    }
    __syncthreads();
    float mu = scal[2];
    int n = blockIdx.x * blockDim.x + threadIdx.x;
    if (n < NN) {
        float a = agg1[n] - mu;
        float h0 = 0.f, h1 = 0.f;
#pragma unroll
        for (int j = 0; j < NH; ++j) {
            float t = fmaxf(fmaf(a, sc[j], sb[j]), 0.f);
            h0 = fmaf(t, s0[j], h0);
            h1 = fmaf(t, s1[j], h1);
        }
        hp[2 * n] = h0; hp[2 * n + 1] = h1;
        float sl = dinv[n] * dinv[n];
        agg2[2 * n] = sl * h0; agg2[2 * n + 1] = sl * h1;
    }
}

__global__ void k_edge_agg2_fb(const int* __restrict__ src, const int* __restrict__ dst,
                               const float* __restrict__ w, const float* __restrict__ dinv,
                               const float* __restrict__ hp, float* __restrict__ agg2) {
    int gid = blockIdx.x * blockDim.x + threadIdx.x;
    int T = gridDim.x * blockDim.x;
    for (int e = gid; e < NE; e += T) {
        int s = src[e], d = dst[e];
        float nrm = dinv[s] * w[e] * dinv[d];
        float2 h = *reinterpret_cast<const float2*>(hp + 2 * s);
        atomicAdd(&agg2[2 * d],     nrm * h.x);
        atomicAdd(&agg2[2 * d + 1], nrm * h.y);
    }
}

// ================= pool + finalize (shared) =================

__global__ void k_pool(const float* __restrict__ agg2, const int* __restrict__ batch,
                       float* __restrict__ pooled, float* __restrict__ cnt) {
    __shared__ float ls0[NG], ls1[NG], lc[NG];
    if (threadIdx.x < NG) { ls0[threadIdx.x] = 0.f; ls1[threadIdx.x] = 0.f; lc[threadIdx.x] = 0.f; }
    __syncthreads();
    int gid = blockIdx.x * blockDim.x + threadIdx.x;
    int T = gridDim.x * blockDim.x;
    int lane = threadIdx.x & 63;
    for (int n = gid; __any(n < NN); n += T) {
        bool valid = n < NN;
        int b = 0; float vx = 0.f, vy = 0.f;
        if (valid) {
            b = batch[n];
            float2 v = *reinterpret_cast<const float2*>(agg2 + 2 * n);
            vx = v.x; vy = v.y;
        }
        int b0 = __shfl(b, 0);
        bool uni = __all(valid ? (b == b0) : 1);
        if (uni) {
            float rc = valid ? 1.f : 0.f;
            for (int off = 32; off > 0; off >>= 1) {
                vx += __shfl_down(vx, off);
                vy += __shfl_down(vy, off);
                rc += __shfl_down(rc, off);
            }
            if (lane == 0) { atomicAdd(&ls0[b0], vx); atomicAdd(&ls1[b0], vy); atomicAdd(&lc[b0], rc); }
        } else if (valid) {
            atomicAdd(&ls0[b], vx); atomicAdd(&ls1[b], vy); atomicAdd(&lc[b], 1.f);
        }
    }
    __syncthreads();
    if (threadIdx.x < NG) {
        int g = threadIdx.x;
        atomicAdd(&pooled[2 * g], ls0[g]);
        atomicAdd(&pooled[2 * g + 1], ls1[g]);
        atomicAdd(&cnt[g], lc[g]);
    }
}

__global__ void k_final(const float* __restrict__ pooled, const float* __restrict__ cnt,
                        const float* __restrict__ b2, float* __restrict__ out) {
    int i = threadIdx.x;
    if (i < 2 * NG) {
        int g = i >> 1, k = i & 1;
        float cg = cnt[g];
        out[i] = pooled[i] / fmaxf(cg, 1.0f) + (cg > 0.f ? b2[k] : 0.f);
    }
}

extern "C" void kernel_launch(void* const* d_in, const int* in_sizes, int n_in,
                              void* d_out, int out_size, void* d_ws, size_t ws_size,
                              hipStream_t stream) {
    const float* x     = (const float*)d_in[0];
    const int*   ei    = (const int*)  d_in[1];
    const float* ew    = (const float*)d_in[2];
    const int*   batch = (const int*)  d_in[3];
    const float* W1    = (const float*)d_in[4];
    const float* gamma = (const float*)d_in[6];
    const float* beta  = (const float*)d_in[7];
    const float* W2    = (const float*)d_in[8];
    const float* b2    = (const float*)d_in[9];
    float* out = (float*)d_out;

    float* ws = (float*)d_ws;
    // persistent arrays (9*NN + small)
    float* dinv   = ws;                 // [NN]
    float* g1     = ws + NN;            // [NN]
    float* agg1   = ws + 2 * NN;        // [NN]
    float* hp     = ws + 3 * NN;        // [2*NN]
    float* g2     = ws + 5 * NN;        // [2*NN]
    float* agg2   = ws + 7 * NN;        // [2*NN]
    float* scal   = ws + 9 * NN;        // [8]
    float* cbuf   = ws + 9 * NN + 8;    // [64]
    float* pooled = ws + 9 * NN + 80;   // [128]
    float* cnt    = ws + 9 * NN + 224;  // [64]
    float* partial = ws + 9 * NN + 288; // [C1*NN] or [C2*2*NN]

    const int* srcp = ei;
    const int* dstp = ei + NE;

    size_t availF = ws_size / sizeof(float);
    size_t persist = 9 * (size_t)NN + 288;
    size_t pf = (availF > persist) ? (availF - persist) : 0;

    const int NB = (NN + TPB - 1) / TPB;

    if (pf >= 2 * (size_t)NN) {
        // ---- gather path ----
        int C1 = (int)(pf / NN);        if (C1 > 32) C1 = 32;
        int C2 = (int)(pf / (2 * NN));  if (C2 > 16) C2 = 16;

        kA_deg     <<<R1 * C1, ETPB, 0, stream>>>(dstp, ew, partial, C1);
        k_reduce_deg<<<NB, TPB, 0, stream>>>(partial, x, dinv, g1, scal, C1);
        kA_t1      <<<R1 * C1, ETPB, 0, stream>>>(srcp, dstp, ew, g1, partial, C1);
        k_reduce_t1<<<NB, TPB, 0, stream>>>(partial, dinv, g1, agg1, scal, C1);
        k_prep     <<<1, 64, 0, stream>>>(scal, W1, gamma, cbuf, pooled, cnt);
        k_node_hp  <<<NB, TPB, 0, stream>>>(agg1, dinv, cbuf, beta, W2, scal, hp, g2);
        kA_t2      <<<R2 * C2, ETPB, 0, stream>>>(srcp, dstp, ew, g2, partial, C2);
        k_reduce_t2<<<NB, TPB, 0, stream>>>(partial, dinv, g2, agg2, C2);
    } else {
        // ---- fallback atomic path (tiny scratch) ----
        const int ebl = 2048;
        hipMemsetAsync(dinv, 0, NN * sizeof(float), stream);
        k_edge_deg_fb <<<ebl, TPB, 0, stream>>>(dstp, ew, dinv);
        k_node_dinv_fb<<<NB, TPB, 0, stream>>>(x, dinv, agg1, scal);
        k_edge_agg1_fb<<<ebl, TPB, 0, stream>>>(srcp, dstp, ew, dinv, x, agg1);
        k_reduce_fb   <<<256, TPB, 0, stream>>>(agg1, scal);
        k_prep        <<<1, 64, 0, stream>>>(scal, W1, gamma, cbuf, pooled, cnt);
        k_node_hp_fb  <<<NB, TPB, 0, stream>>>(agg1, dinv, cbuf, beta, W2, scal, hp, agg2);
        k_edge_agg2_fb<<<ebl, TPB, 0, stream>>>(srcp, dstp, ew, dinv, hp, agg2);
    }

    k_pool <<<128, TPB, 0, stream>>>(agg2, batch, pooled, cnt);
    k_final<<<1, 128, 0, stream>>>(pooled, cnt, b2, out);
}

// Round 3
// 189.954 us; speedup vs baseline: 2.0700x; 1.1571x over previous
//
#include <hip/hip_runtime.h>

#define NN 100000
#define NE 1600000
#define NH 64
#define NG 64

#define RNG1 16384  // range width for scalar gather passes (deg, t1) -> 64KB LDS
#define R1   7      // ceil(NN/RNG1)
#define RNG2 8192   // range width for 2-wide gather pass (t2) -> 64KB LDS (float2)
#define R2   13     // ceil(NN/RNG2)

#define C1MAX 74    // grid = R1*C1 ~ 518 blocks
#define C2MAX 40    // grid = R2*C2 ~ 520 blocks

static constexpr int TPB  = 256;    // node kernels
static constexpr int ETPB = 1024;   // edge-stream kernels: 16 waves/block

// ================= gather path =================

// pass A1: partial_deg[c][n] = sum of w over edges in chunk c with dst==n (n in range r)
__global__ __launch_bounds__(ETPB) void kA_deg(const int* __restrict__ dst,
                                               const float* __restrict__ w,
                                               float* __restrict__ partial, int C) {
    __shared__ float bins[RNG1];
    int r = blockIdx.x / C, c = blockIdx.x % C;
    int base = r * RNG1;
    for (int i = threadIdx.x; i < RNG1; i += blockDim.x) bins[i] = 0.f;
    __syncthreads();
    long e0 = ((long)c * NE / C) & ~3L;
    long e1 = (c == C - 1) ? NE : (((long)(c + 1) * NE / C) & ~3L);
    for (long e = e0 + (long)threadIdx.x * 4; e < e1; e += (long)blockDim.x * 4) {
        int4 d4 = *reinterpret_cast<const int4*>(dst + e);
        int ds[4] = {d4.x, d4.y, d4.z, d4.w};
#pragma unroll
        for (int k = 0; k < 4; ++k) {
            unsigned off = (unsigned)(ds[k] - base);
            if (off < (unsigned)RNG1) atomicAdd(&bins[off], w[e + k]);
        }
    }
    __syncthreads();
    int len = min(RNG1, NN - base);
    for (int i = threadIdx.x; i < len; i += blockDim.x)
        partial[(size_t)c * NN + base + i] = bins[i];
}

// reduce deg partials -> dinv = rsqrt(deg+1); g1 = dinv*x; zero BN accumulators
__global__ void k_reduce_deg(const float* __restrict__ partial, const float* __restrict__ x,
                             float* __restrict__ dinv, float* __restrict__ g1,
                             float* __restrict__ scal, int C) {
    int n = blockIdx.x * blockDim.x + threadIdx.x;
    if (n < NN) {
        float s = 0.f;
        for (int c = 0; c < C; ++c) s += partial[(size_t)c * NN + n];
        float di = rsqrtf(s + 1.0f);
        dinv[n] = di;
        g1[n] = di * x[n];
    }
    if (blockIdx.x == 0 && threadIdx.x == 0) { scal[0] = 0.f; scal[1] = 0.f; }
}

// pass A2: partial_t1[c][n] = sum of w * g1[src] over edges with dst==n
__global__ __launch_bounds__(ETPB) void kA_t1(const int* __restrict__ src,
                                              const int* __restrict__ dst,
                                              const float* __restrict__ w,
                                              const float* __restrict__ g1,
                                              float* __restrict__ partial, int C) {
    __shared__ float bins[RNG1];
    int r = blockIdx.x / C, c = blockIdx.x % C;
    int base = r * RNG1;
    for (int i = threadIdx.x; i < RNG1; i += blockDim.x) bins[i] = 0.f;
    __syncthreads();
    long e0 = ((long)c * NE / C) & ~3L;
    long e1 = (c == C - 1) ? NE : (((long)(c + 1) * NE / C) & ~3L);
    for (long e = e0 + (long)threadIdx.x * 4; e < e1; e += (long)blockDim.x * 4) {
        int4 d4 = *reinterpret_cast<const int4*>(dst + e);
        int ds[4] = {d4.x, d4.y, d4.z, d4.w};
#pragma unroll
        for (int k = 0; k < 4; ++k) {
            unsigned off = (unsigned)(ds[k] - base);
            if (off < (unsigned)RNG1) {
                int s = src[e + k];
                atomicAdd(&bins[off], w[e + k] * g1[s]);
            }
        }
    }
    __syncthreads();
    int len = min(RNG1, NN - base);
    for (int i = threadIdx.x; i < len; i += blockDim.x)
        partial[(size_t)c * NN + base + i] = bins[i];
}

// reduce t1 partials -> agg1 = dinv*(t1 + g1); accumulate BN sum/sumsq
__global__ void k_reduce_t1(const float* __restrict__ partial, const float* __restrict__ dinv,
                            const float* __restrict__ g1, float* __restrict__ agg1,
                            float* __restrict__ scal, int C) {
    int n = blockIdx.x * blockDim.x + threadIdx.x;
    float a = 0.f;
    if (n < NN) {
        float t = 0.f;
        for (int c = 0; c < C; ++c) t += partial[(size_t)c * NN + n];
        a = dinv[n] * (t + g1[n]);
        agg1[n] = a;
    }
    float s = a, q = a * a;
    for (int off = 32; off > 0; off >>= 1) {
        s += __shfl_down(s, off);
        q += __shfl_down(q, off);
    }
    __shared__ float red[2][4];
    int wave = threadIdx.x >> 6, lane = threadIdx.x & 63;
    if (lane == 0) { red[0][wave] = s; red[1][wave] = q; }
    __syncthreads();
    if (threadIdx.x == 0) {
        atomicAdd(&scal[0], red[0][0] + red[0][1] + red[0][2] + red[0][3]);
        atomicAdd(&scal[1], red[1][0] + red[1][1] + red[1][2] + red[1][3]);
    }
}

// tiny prep: c[j] = W1[j]*gamma[j]*rsqrt(var*W1[j]^2+eps); zero pool accumulators
__global__ void k_prep(float* __restrict__ scal, const float* __restrict__ W1,
                       const float* __restrict__ gamma, float* __restrict__ c,
                       float* __restrict__ pooled, float* __restrict__ cnt) {
    int j = threadIdx.x;   // 64 threads
    float mu  = scal[0] * (1.0f / NN);
    float var = scal[1] * (1.0f / NN) - mu * mu;
    float w1 = W1[j];
    c[j] = w1 * gamma[j] * rsqrtf(var * w1 * w1 + 1e-5f);
    pooled[2 * j] = 0.f; pooled[2 * j + 1] = 0.f; cnt[j] = 0.f;
    if (j == 0) scal[2] = mu;
}

// node pass: hp[n][k] = sum_j relu((agg1-mu)*c[j]+beta[j]) * W2[j][k]; g2 = dinv*hp
__global__ void k_node_hp(const float* __restrict__ agg1, const float* __restrict__ dinv,
                          const float* __restrict__ c, const float* __restrict__ beta,
                          const float* __restrict__ W2, const float* __restrict__ scal,
                          float* __restrict__ hp, float* __restrict__ g2) {
    __shared__ float sc[NH], sb[NH], s0[NH], s1[NH];
    if (threadIdx.x < NH) {
        int j = threadIdx.x;
        sc[j] = c[j]; sb[j] = beta[j]; s0[j] = W2[2 * j]; s1[j] = W2[2 * j + 1];
    }
    __syncthreads();
    float mu = scal[2];
    int n = blockIdx.x * blockDim.x + threadIdx.x;
    if (n < NN) {
        float a = agg1[n] - mu;
        float h0 = 0.f, h1 = 0.f;
#pragma unroll
        for (int j = 0; j < NH; ++j) {
            float t = fmaxf(fmaf(a, sc[j], sb[j]), 0.f);
            h0 = fmaf(t, s0[j], h0);
            h1 = fmaf(t, s1[j], h1);
        }
        hp[2 * n] = h0; hp[2 * n + 1] = h1;
        float di = dinv[n];
        g2[2 * n] = di * h0; g2[2 * n + 1] = di * h1;
    }
}

// pass A3: partial_t2[c][k][n] = sum of w * g2[src][k] over edges with dst==n
__global__ __launch_bounds__(ETPB) void kA_t2(const int* __restrict__ src,
                                              const int* __restrict__ dst,
                                              const float* __restrict__ w,
                                              const float* __restrict__ g2,
                                              float* __restrict__ partial, int C) {
    __shared__ float2 bins[RNG2];
    int r = blockIdx.x / C, c = blockIdx.x % C;
    int base = r * RNG2;
    for (int i = threadIdx.x; i < RNG2; i += blockDim.x) bins[i] = make_float2(0.f, 0.f);
    __syncthreads();
    long e0 = ((long)c * NE / C) & ~3L;
    long e1 = (c == C - 1) ? NE : (((long)(c + 1) * NE / C) & ~3L);
    for (long e = e0 + (long)threadIdx.x * 4; e < e1; e += (long)blockDim.x * 4) {
        int4 d4 = *reinterpret_cast<const int4*>(dst + e);
        int ds[4] = {d4.x, d4.y, d4.z, d4.w};
#pragma unroll
        for (int k = 0; k < 4; ++k) {
            unsigned off = (unsigned)(ds[k] - base);
            if (off < (unsigned)RNG2) {
                int s = src[e + k];
                float ww = w[e + k];
                float2 g = *reinterpret_cast<const float2*>(g2 + 2 * s);
                atomicAdd(&bins[off].x, ww * g.x);
                atomicAdd(&bins[off].y, ww * g.y);
            }
        }
    }
    __syncthreads();
    int len = min(RNG2, NN - base);
    for (int i = threadIdx.x; i < len; i += blockDim.x) {
        float2 b = bins[i];
        partial[((size_t)(2 * c))     * NN + base + i] = b.x;
        partial[((size_t)(2 * c + 1)) * NN + base + i] = b.y;
    }
}

// reduce t2 partials -> agg2 = dinv*(t2 + g2)
__global__ void k_reduce_t2(const float* __restrict__ partial, const float* __restrict__ dinv,
                            const float* __restrict__ g2, float* __restrict__ agg2, int C) {
    int n = blockIdx.x * blockDim.x + threadIdx.x;
    if (n < NN) {
        float tx = 0.f, ty = 0.f;
        for (int c = 0; c < C; ++c) {
            tx += partial[((size_t)(2 * c))     * NN + n];
            ty += partial[((size_t)(2 * c + 1)) * NN + n];
        }
        float di = dinv[n];
        agg2[2 * n]     = di * (tx + g2[2 * n]);
        agg2[2 * n + 1] = di * (ty + g2[2 * n + 1]);
    }
}

// ================= fallback (atomic) path, used only if scratch is tiny =================

__global__ void k_edge_deg_fb(const int* __restrict__ dst, const float* __restrict__ w,
                              float* __restrict__ deg) {
    int gid = blockIdx.x * blockDim.x + threadIdx.x;
    int T = gridDim.x * blockDim.x;
    for (int e = gid; e < NE; e += T) atomicAdd(&deg[dst[e]], w[e]);
}

__global__ void k_node_dinv_fb(const float* __restrict__ x, float* __restrict__ deg,
                               float* __restrict__ agg1, float* __restrict__ scal) {
    int gid = blockIdx.x * blockDim.x + threadIdx.x;
    int T = gridDim.x * blockDim.x;
    for (int n = gid; n < NN; n += T) {
        float di = rsqrtf(deg[n] + 1.0f);
        deg[n] = di;
        agg1[n] = di * di * x[n];
    }
    if (gid == 0) { scal[0] = 0.f; scal[1] = 0.f; }
}

__global__ void k_edge_agg1_fb(const int* __restrict__ src, const int* __restrict__ dst,
                               const float* __restrict__ w, const float* __restrict__ dinv,
                               const float* __restrict__ x, float* __restrict__ agg1) {
    int gid = blockIdx.x * blockDim.x + threadIdx.x;
    int T = gridDim.x * blockDim.x;
    for (int e = gid; e < NE; e += T) {
        int s = src[e], d = dst[e];
        atomicAdd(&agg1[d], dinv[s] * w[e] * dinv[d] * x[s]);
    }
}

__global__ void k_reduce_fb(const float* __restrict__ agg1, float* __restrict__ scal) {
    float s = 0.f, q = 0.f;
    int gid = blockIdx.x * blockDim.x + threadIdx.x;
    int T = gridDim.x * blockDim.x;
    for (int n = gid; n < NN; n += T) { float a = agg1[n]; s += a; q += a * a; }
    for (int off = 32; off > 0; off >>= 1) { s += __shfl_down(s, off); q += __shfl_down(q, off); }
    __shared__ float red[2][4];
    int wave = threadIdx.x >> 6, lane = threadIdx.x & 63;
    if (lane == 0) { red[0][wave] = s; red[1][wave] = q; }
    __syncthreads();
    if (threadIdx.x == 0) {
        atomicAdd(&scal[0], red[0][0] + red[0][1] + red[0][2] + red[0][3]);
        atomicAdd(&scal[1], red[1][0] + red[1][1] + red[1][2] + red[1][3]);
    }
}

__global__ void k_node_hp_fb(const float* __restrict__ agg1, const float* __restrict__ dinv,
                             const float* __restrict__ c, const float* __restrict__ beta,
                             const float* __restrict__ W2, const float* __restrict__ scal,
                             float* __restrict__ hp, float* __restrict__ agg2) {
    __shared__ float sc[NH], sb[NH], s0[NH], s1[NH];
    if (threadIdx.x < NH) {
        int j = threadIdx.x;
        sc[j] = c[j]; sb[j] = beta[j]; s0[j] = W2[2 * j]; s1[j] = W2[2 * j + 1];
    }
    __syncthreads();
    float mu = scal[2];
    int n = blockIdx.x * blockDim.x + threadIdx.x;
    if (n < NN) {
        float a = agg1[n] - mu;
        float h0 = 0.f, h1 = 0.f;
#pragma unroll
        for (int j = 0; j < NH; ++j) {
            float t = fmaxf(fmaf(a, sc[j], sb[j]), 0.f);
            h0 = fmaf(t, s0[j], h0);
            h1 = fmaf(t, s1[j], h1);
        }
        hp[2 * n] = h0; hp[2 * n + 1] = h1;
        float sl = dinv[n] * dinv[n];
        agg2[2 * n] = sl * h0; agg2[2 * n + 1] = sl * h1;
    }
}

__global__ void k_edge_agg2_fb(const int* __restrict__ src, const int* __restrict__ dst,
                               const float* __restrict__ w, const float* __restrict__ dinv,
                               const float* __restrict__ hp, float* __restrict__ agg2) {
    int gid = blockIdx.x * blockDim.x + threadIdx.x;
    int T = gridDim.x * blockDim.x;
    for (int e = gid; e < NE; e += T) {
        int s = src[e], d = dst[e];
        float nrm = dinv[s] * w[e] * dinv[d];
        float2 h = *reinterpret_cast<const float2*>(hp + 2 * s);
        atomicAdd(&agg2[2 * d],     nrm * h.x);
        atomicAdd(&agg2[2 * d + 1], nrm * h.y);
    }
}

// ================= pool + finalize (shared) =================

__global__ void k_pool(const float* __restrict__ agg2, const int* __restrict__ batch,
                       float* __restrict__ pooled, float* __restrict__ cnt) {
    __shared__ float ls0[NG], ls1[NG], lc[NG];
    if (threadIdx.x < NG) { ls0[threadIdx.x] = 0.f; ls1[threadIdx.x] = 0.f; lc[threadIdx.x] = 0.f; }
    __syncthreads();
    int gid = blockIdx.x * blockDim.x + threadIdx.x;
    int T = gridDim.x * blockDim.x;
    int lane = threadIdx.x & 63;
    for (int n = gid; __any(n < NN); n += T) {
        bool valid = n < NN;
        int b = 0; float vx = 0.f, vy = 0.f;
        if (valid) {
            b = batch[n];
            float2 v = *reinterpret_cast<const float2*>(agg2 + 2 * n);
            vx = v.x; vy = v.y;
        }
        int b0 = __shfl(b, 0);
        bool uni = __all(valid ? (b == b0) : 1);
        if (uni) {
            float rc = valid ? 1.f : 0.f;
            for (int off = 32; off > 0; off >>= 1) {
                vx += __shfl_down(vx, off);
                vy += __shfl_down(vy, off);
                rc += __shfl_down(rc, off);
            }
            if (lane == 0) { atomicAdd(&ls0[b0], vx); atomicAdd(&ls1[b0], vy); atomicAdd(&lc[b0], rc); }
        } else if (valid) {
            atomicAdd(&ls0[b], vx); atomicAdd(&ls1[b], vy); atomicAdd(&lc[b], 1.f);
        }
    }
    __syncthreads();
    if (threadIdx.x < NG) {
        int g = threadIdx.x;
        atomicAdd(&pooled[2 * g], ls0[g]);
        atomicAdd(&pooled[2 * g + 1], ls1[g]);
        atomicAdd(&cnt[g], lc[g]);
    }
}

__global__ void k_final(const float* __restrict__ pooled, const float* __restrict__ cnt,
                        const float* __restrict__ b2, float* __restrict__ out) {
    int i = threadIdx.x;
    if (i < 2 * NG) {
        int g = i >> 1, k = i & 1;
        float cg = cnt[g];
        out[i] = pooled[i] / fmaxf(cg, 1.0f) + (cg > 0.f ? b2[k] : 0.f);
    }
}

extern "C" void kernel_launch(void* const* d_in, const int* in_sizes, int n_in,
                              void* d_out, int out_size, void* d_ws, size_t ws_size,
                              hipStream_t stream) {
    const float* x     = (const float*)d_in[0];
    const int*   ei    = (const int*)  d_in[1];
    const float* ew    = (const float*)d_in[2];
    const int*   batch = (const int*)  d_in[3];
    const float* W1    = (const float*)d_in[4];
    const float* gamma = (const float*)d_in[6];
    const float* beta  = (const float*)d_in[7];
    const float* W2    = (const float*)d_in[8];
    const float* b2    = (const float*)d_in[9];
    float* out = (float*)d_out;

    float* ws = (float*)d_ws;
    // persistent arrays (9*NN + small)
    float* dinv   = ws;                 // [NN]
    float* g1     = ws + NN;            // [NN]
    float* agg1   = ws + 2 * NN;        // [NN]
    float* hp     = ws + 3 * NN;        // [2*NN]
    float* g2     = ws + 5 * NN;        // [2*NN]
    float* agg2   = ws + 7 * NN;        // [2*NN]
    float* scal   = ws + 9 * NN;        // [8]
    float* cbuf   = ws + 9 * NN + 8;    // [64]
    float* pooled = ws + 9 * NN + 80;   // [128]
    float* cnt    = ws + 9 * NN + 224;  // [64]
    float* partial = ws + 9 * NN + 288; // [C1*NN] or [C2*2*NN]

    const int* srcp = ei;
    const int* dstp = ei + NE;

    size_t availF = ws_size / sizeof(float);
    size_t persist = 9 * (size_t)NN + 288;
    size_t pf = (availF > persist) ? (availF - persist) : 0;

    const int NB = (NN + TPB - 1) / TPB;

    if (pf >= 2 * (size_t)NN) {
        // ---- gather path ----
        int C1 = (int)(pf / NN);        if (C1 > C1MAX) C1 = C1MAX;
        int C2 = (int)(pf / (2 * NN));  if (C2 > C2MAX) C2 = C2MAX;

        kA_deg     <<<R1 * C1, ETPB, 0, stream>>>(dstp, ew, partial, C1);
        k_reduce_deg<<<NB, TPB, 0, stream>>>(partial, x, dinv, g1, scal, C1);
        kA_t1      <<<R1 * C1, ETPB, 0, stream>>>(srcp, dstp, ew, g1, partial, C1);
        k_reduce_t1<<<NB, TPB, 0, stream>>>(partial, dinv, g1, agg1, scal, C1);
        k_prep     <<<1, 64, 0, stream>>>(scal, W1, gamma, cbuf, pooled, cnt);
        k_node_hp  <<<NB, TPB, 0, stream>>>(agg1, dinv, cbuf, beta, W2, scal, hp, g2);
        kA_t2      <<<R2 * C2, ETPB, 0, stream>>>(srcp, dstp, ew, g2, partial, C2);
        k_reduce_t2<<<NB, TPB, 0, stream>>>(partial, dinv, g2, agg2, C2);
    } else {
        // ---- fallback atomic path (tiny scratch) ----
        const int ebl = 2048;
        hipMemsetAsync(dinv, 0, NN * sizeof(float), stream);
        k_edge_deg_fb <<<ebl, TPB, 0, stream>>>(dstp, ew, dinv);
        k_node_dinv_fb<<<NB, TPB, 0, stream>>>(x, dinv, agg1, scal);
        k_edge_agg1_fb<<<ebl, TPB, 0, stream>>>(srcp, dstp, ew, dinv, x, agg1);
        k_reduce_fb   <<<256, TPB, 0, stream>>>(agg1, scal);
        k_prep        <<<1, 64, 0, stream>>>(scal, W1, gamma, cbuf, pooled, cnt);
        k_node_hp_fb  <<<NB, TPB, 0, stream>>>(agg1, dinv, cbuf, beta, W2, scal, hp, agg2);
        k_edge_agg2_fb<<<ebl, TPB, 0, stream>>>(srcp, dstp, ew, dinv, hp, agg2);
    }

    k_pool <<<128, TPB, 0, stream>>>(agg2, batch, pooled, cnt);
    k_final<<<1, 128, 0, stream>>>(pooled, cnt, b2, out);
}

// Round 4
// 135.672 us; speedup vs baseline: 2.8981x; 1.4001x over previous
//
#include <hip/hip_runtime.h>

#define NN 100000
#define NE 1600000
#define NH 64
#define NG 64

#define RNG   8192   // bucket/range width (2^13)
#define RB    13     // ceil(NN/RNG)
#define BB    256    // bucketing blocks
#define CSMAX 32     // chunks per bucket, scalar passes (partial = 32*NN)
#define C2MAX 16     // chunks per bucket, t2 pass      (partial = 32*NN)

static constexpr int TPB = 256;    // node kernels

// ================= bucket build =================

// count per (block, bucket)
__global__ __launch_bounds__(1024) void k_count(const int* __restrict__ dst,
                                                int* __restrict__ cntmat) {
    __shared__ int cl[RB];
    if (threadIdx.x < RB) cl[threadIdx.x] = 0;
    __syncthreads();
    int b = blockIdx.x;
    long e0 = ((long)b * NE / BB) & ~3L;
    long e1 = (b == BB - 1) ? NE : (((long)(b + 1) * NE / BB) & ~3L);
    for (long e = e0 + (long)threadIdx.x * 4; e < e1; e += (long)blockDim.x * 4) {
        int4 d4 = *reinterpret_cast<const int4*>(dst + e);
        atomicAdd(&cl[d4.x >> 13], 1);
        atomicAdd(&cl[d4.y >> 13], 1);
        atomicAdd(&cl[d4.z >> 13], 1);
        atomicAdd(&cl[d4.w >> 13], 1);
    }
    __syncthreads();
    if (threadIdx.x < RB) cntmat[b * RB + threadIdx.x] = cl[threadIdx.x];
}

// scan: per-(block,bucket) start offsets + bucket offsets/sizes. 1 block, 13 waves.
__global__ __launch_bounds__(832) void k_scan(const int* __restrict__ cntmat,
                                              int* __restrict__ startmat,
                                              int* __restrict__ bmeta) {
    __shared__ int mat[BB][RB];
    __shared__ int tot[RB];
    __shared__ int boff[RB + 1];
    int w = threadIdx.x >> 6, lane = threadIdx.x & 63;   // w in [0,13)
    int carry = 0;
    for (int i = 0; i < BB / 64; ++i) {
        int b = i * 64 + lane;
        int v = cntmat[b * RB + w];
        int inc = v;
        for (int off = 1; off < 64; off <<= 1) {
            int t = __shfl_up(inc, off);
            if (lane >= off) inc += t;
        }
        mat[b][w] = carry + (inc - v);
        carry += __shfl(inc, 63);
    }
    if (lane == 0) tot[w] = carry;
    __syncthreads();
    if (threadIdx.x == 0) {
        int acc = 0;
        for (int r = 0; r < RB; ++r) { boff[r] = acc; acc += tot[r]; }
        boff[RB] = acc;
        for (int r = 0; r <= RB; ++r) bmeta[r] = boff[r];
        for (int r = 0; r < RB; ++r) bmeta[16 + r] = tot[r];
    }
    __syncthreads();
    for (int i = 0; i < BB / 64; ++i) {
        int b = i * 64 + lane;
        startmat[b * RB + w] = mat[b][w] + boff[w];
    }
}

// scatter edges into buckets: ebuf[slot] = { (dstoff<<17)|src , w }
__global__ __launch_bounds__(1024) void k_scatter(const int* __restrict__ src,
                                                  const int* __restrict__ dst,
                                                  const float* __restrict__ w,
                                                  const int* __restrict__ startmat,
                                                  uint2* __restrict__ ebuf) {
    __shared__ int curs[RB];
    int b = blockIdx.x;
    if (threadIdx.x < RB) curs[threadIdx.x] = startmat[b * RB + threadIdx.x];
    __syncthreads();
    long e0 = ((long)b * NE / BB) & ~3L;
    long e1 = (b == BB - 1) ? NE : (((long)(b + 1) * NE / BB) & ~3L);
    for (long e = e0 + (long)threadIdx.x * 4; e < e1; e += (long)blockDim.x * 4) {
        int4 d4 = *reinterpret_cast<const int4*>(dst + e);
        int4 s4 = *reinterpret_cast<const int4*>(src + e);
        float4 w4 = *reinterpret_cast<const float4*>(w + e);
        int dd[4] = {d4.x, d4.y, d4.z, d4.w};
        int ss[4] = {s4.x, s4.y, s4.z, s4.w};
        float wv[4] = {w4.x, w4.y, w4.z, w4.w};
#pragma unroll
        for (int k = 0; k < 4; ++k) {
            int r = dd[k] >> 13;
            int slot = atomicAdd(&curs[r], 1);
            unsigned pack = ((unsigned)(dd[k] & (RNG - 1)) << 17) | (unsigned)ss[k];
            ebuf[slot] = make_uint2(pack, __float_as_uint(wv[k]));
        }
    }
}

// ================= bucketed gather passes =================

// deg: bins[off] += w  (100% hit rate)
__global__ __launch_bounds__(1024) void kB_deg(const uint2* __restrict__ ebuf,
                                               const int* __restrict__ bmeta,
                                               float* __restrict__ partial, int C) {
    __shared__ float bins[RNG];
    int r = blockIdx.x / C, c = blockIdx.x % C;
    for (int i = threadIdx.x; i < RNG; i += blockDim.x) bins[i] = 0.f;
    __syncthreads();
    long b0 = bmeta[r]; long sz = bmeta[16 + r];
    long s = b0 + sz * c / C, e = b0 + sz * (c + 1) / C;
    for (long i = s + threadIdx.x; i < e; i += blockDim.x) {
        uint2 ed = ebuf[i];
        atomicAdd(&bins[ed.x >> 17], __uint_as_float(ed.y));
    }
    __syncthreads();
    int base = r * RNG;
    int len = min(RNG, NN - base);
    for (int i = threadIdx.x; i < len; i += blockDim.x)
        partial[(size_t)c * NN + base + i] = bins[i];
}

// t1: bins[off] += w * g1[src]
__global__ __launch_bounds__(1024) void kB_t1(const uint2* __restrict__ ebuf,
                                              const int* __restrict__ bmeta,
                                              const float* __restrict__ g1,
                                              float* __restrict__ partial, int C) {
    __shared__ float bins[RNG];
    int r = blockIdx.x / C, c = blockIdx.x % C;
    for (int i = threadIdx.x; i < RNG; i += blockDim.x) bins[i] = 0.f;
    __syncthreads();
    long b0 = bmeta[r]; long sz = bmeta[16 + r];
    long s = b0 + sz * c / C, e = b0 + sz * (c + 1) / C;
    for (long i = s + threadIdx.x; i < e; i += blockDim.x) {
        uint2 ed = ebuf[i];
        int sidx = ed.x & 0x1FFFF;
        atomicAdd(&bins[ed.x >> 17], __uint_as_float(ed.y) * g1[sidx]);
    }
    __syncthreads();
    int base = r * RNG;
    int len = min(RNG, NN - base);
    for (int i = threadIdx.x; i < len; i += blockDim.x)
        partial[(size_t)c * NN + base + i] = bins[i];
}

// t2: bins[off] += w * g2[src][0..1]
__global__ __launch_bounds__(1024) void kB_t2(const uint2* __restrict__ ebuf,
                                              const int* __restrict__ bmeta,
                                              const float* __restrict__ g2,
                                              float* __restrict__ partial, int C) {
    __shared__ float2 bins[RNG];
    int r = blockIdx.x / C, c = blockIdx.x % C;
    for (int i = threadIdx.x; i < RNG; i += blockDim.x) bins[i] = make_float2(0.f, 0.f);
    __syncthreads();
    long b0 = bmeta[r]; long sz = bmeta[16 + r];
    long s = b0 + sz * c / C, e = b0 + sz * (c + 1) / C;
    for (long i = s + threadIdx.x; i < e; i += blockDim.x) {
        uint2 ed = ebuf[i];
        int sidx = ed.x & 0x1FFFF;
        float ww = __uint_as_float(ed.y);
        float2 g = *reinterpret_cast<const float2*>(g2 + 2 * sidx);
        int off = ed.x >> 17;
        atomicAdd(&bins[off].x, ww * g.x);
        atomicAdd(&bins[off].y, ww * g.y);
    }
    __syncthreads();
    int base = r * RNG;
    int len = min(RNG, NN - base);
    for (int i = threadIdx.x; i < len; i += blockDim.x) {
        float2 b = bins[i];
        partial[((size_t)(2 * c))     * NN + base + i] = b.x;
        partial[((size_t)(2 * c + 1)) * NN + base + i] = b.y;
    }
}

// ================= node / reduce kernels =================

__global__ void k_reduce_deg(const float* __restrict__ partial, const float* __restrict__ x,
                             float* __restrict__ dinv, float* __restrict__ g1,
                             float* __restrict__ scal, int C) {
    int n = blockIdx.x * blockDim.x + threadIdx.x;
    if (n < NN) {
        float s = 0.f;
        for (int c = 0; c < C; ++c) s += partial[(size_t)c * NN + n];
        float di = rsqrtf(s + 1.0f);
        dinv[n] = di;
        g1[n] = di * x[n];
    }
    if (blockIdx.x == 0 && threadIdx.x == 0) { scal[0] = 0.f; scal[1] = 0.f; }
}

__global__ void k_reduce_t1(const float* __restrict__ partial, const float* __restrict__ dinv,
                            const float* __restrict__ g1, float* __restrict__ agg1,
                            float* __restrict__ scal, int C) {
    int n = blockIdx.x * blockDim.x + threadIdx.x;
    float a = 0.f;
    if (n < NN) {
        float t = 0.f;
        for (int c = 0; c < C; ++c) t += partial[(size_t)c * NN + n];
        a = dinv[n] * (t + g1[n]);
        agg1[n] = a;
    }
    float s = a, q = a * a;
    for (int off = 32; off > 0; off >>= 1) {
        s += __shfl_down(s, off);
        q += __shfl_down(q, off);
    }
    __shared__ float red[2][4];
    int wave = threadIdx.x >> 6, lane = threadIdx.x & 63;
    if (lane == 0) { red[0][wave] = s; red[1][wave] = q; }
    __syncthreads();
    if (threadIdx.x == 0) {
        atomicAdd(&scal[0], red[0][0] + red[0][1] + red[0][2] + red[0][3]);
        atomicAdd(&scal[1], red[1][0] + red[1][1] + red[1][2] + red[1][3]);
    }
}

__global__ void k_prep(float* __restrict__ scal, const float* __restrict__ W1,
                       const float* __restrict__ gamma, float* __restrict__ c,
                       float* __restrict__ pooled, float* __restrict__ cnt) {
    int j = threadIdx.x;   // 64 threads
    float mu  = scal[0] * (1.0f / NN);
    float var = scal[1] * (1.0f / NN) - mu * mu;
    float w1 = W1[j];
    c[j] = w1 * gamma[j] * rsqrtf(var * w1 * w1 + 1e-5f);
    pooled[2 * j] = 0.f; pooled[2 * j + 1] = 0.f; cnt[j] = 0.f;
    if (j == 0) scal[2] = mu;
}

__global__ void k_node_hp(const float* __restrict__ agg1, const float* __restrict__ dinv,
                          const float* __restrict__ c, const float* __restrict__ beta,
                          const float* __restrict__ W2, const float* __restrict__ scal,
                          float* __restrict__ hp, float* __restrict__ g2) {
    __shared__ float sc[NH], sb[NH], s0[NH], s1[NH];
    if (threadIdx.x < NH) {
        int j = threadIdx.x;
        sc[j] = c[j]; sb[j] = beta[j]; s0[j] = W2[2 * j]; s1[j] = W2[2 * j + 1];
    }
    __syncthreads();
    float mu = scal[2];
    int n = blockIdx.x * blockDim.x + threadIdx.x;
    if (n < NN) {
        float a = agg1[n] - mu;
        float h0 = 0.f, h1 = 0.f;
#pragma unroll
        for (int j = 0; j < NH; ++j) {
            float t = fmaxf(fmaf(a, sc[j], sb[j]), 0.f);
            h0 = fmaf(t, s0[j], h0);
            h1 = fmaf(t, s1[j], h1);
        }
        hp[2 * n] = h0; hp[2 * n + 1] = h1;
        float di = dinv[n];
        g2[2 * n] = di * h0; g2[2 * n + 1] = di * h1;
    }
}

__global__ void k_reduce_t2(const float* __restrict__ partial, const float* __restrict__ dinv,
                            const float* __restrict__ g2, float* __restrict__ agg2, int C) {
    int n = blockIdx.x * blockDim.x + threadIdx.x;
    if (n < NN) {
        float tx = 0.f, ty = 0.f;
        for (int c = 0; c < C; ++c) {
            tx += partial[((size_t)(2 * c))     * NN + n];
            ty += partial[((size_t)(2 * c + 1)) * NN + n];
        }
        float di = dinv[n];
        agg2[2 * n]     = di * (tx + g2[2 * n]);
        agg2[2 * n + 1] = di * (ty + g2[2 * n + 1]);
    }
}

// ================= fallback (atomic) path, used only if scratch is tiny =================

__global__ void k_edge_deg_fb(const int* __restrict__ dst, const float* __restrict__ w,
                              float* __restrict__ deg) {
    int gid = blockIdx.x * blockDim.x + threadIdx.x;
    int T = gridDim.x * blockDim.x;
    for (int e = gid; e < NE; e += T) atomicAdd(&deg[dst[e]], w[e]);
}

__global__ void k_node_dinv_fb(const float* __restrict__ x, float* __restrict__ deg,
                               float* __restrict__ agg1, float* __restrict__ scal) {
    int gid = blockIdx.x * blockDim.x + threadIdx.x;
    int T = gridDim.x * blockDim.x;
    for (int n = gid; n < NN; n += T) {
        float di = rsqrtf(deg[n] + 1.0f);
        deg[n] = di;
        agg1[n] = di * di * x[n];
    }
    if (gid == 0) { scal[0] = 0.f; scal[1] = 0.f; }
}

__global__ void k_edge_agg1_fb(const int* __restrict__ src, const int* __restrict__ dst,
                               const float* __restrict__ w, const float* __restrict__ dinv,
                               const float* __restrict__ x, float* __restrict__ agg1) {
    int gid = blockIdx.x * blockDim.x + threadIdx.x;
    int T = gridDim.x * blockDim.x;
    for (int e = gid; e < NE; e += T) {
        int s = src[e], d = dst[e];
        atomicAdd(&agg1[d], dinv[s] * w[e] * dinv[d] * x[s]);
    }
}

__global__ void k_reduce_fb(const float* __restrict__ agg1, float* __restrict__ scal) {
    float s = 0.f, q = 0.f;
    int gid = blockIdx.x * blockDim.x + threadIdx.x;
    int T = gridDim.x * blockDim.x;
    for (int n = gid; n < NN; n += T) { float a = agg1[n]; s += a; q += a * a; }
    for (int off = 32; off > 0; off >>= 1) { s += __shfl_down(s, off); q += __shfl_down(q, off); }
    __shared__ float red[2][4];
    int wave = threadIdx.x >> 6, lane = threadIdx.x & 63;
    if (lane == 0) { red[0][wave] = s; red[1][wave] = q; }
    __syncthreads();
    if (threadIdx.x == 0) {
        atomicAdd(&scal[0], red[0][0] + red[0][1] + red[0][2] + red[0][3]);
        atomicAdd(&scal[1], red[1][0] + red[1][1] + red[1][2] + red[1][3]);
    }
}

__global__ void k_node_hp_fb(const float* __restrict__ agg1, const float* __restrict__ dinv,
                             const float* __restrict__ c, const float* __restrict__ beta,
                             const float* __restrict__ W2, const float* __restrict__ scal,
                             float* __restrict__ hp, float* __restrict__ agg2) {
    __shared__ float sc[NH], sb[NH], s0[NH], s1[NH];
    if (threadIdx.x < NH) {
        int j = threadIdx.x;
        sc[j] = c[j]; sb[j] = beta[j]; s0[j] = W2[2 * j]; s1[j] = W2[2 * j + 1];
    }
    __syncthreads();
    float mu = scal[2];
    int n = blockIdx.x * blockDim.x + threadIdx.x;
    if (n < NN) {
        float a = agg1[n] - mu;
        float h0 = 0.f, h1 = 0.f;
#pragma unroll
        for (int j = 0; j < NH; ++j) {
            float t = fmaxf(fmaf(a, sc[j], sb[j]), 0.f);
            h0 = fmaf(t, s0[j], h0);
            h1 = fmaf(t, s1[j], h1);
        }
        hp[2 * n] = h0; hp[2 * n + 1] = h1;
        float sl = dinv[n] * dinv[n];
        agg2[2 * n] = sl * h0; agg2[2 * n + 1] = sl * h1;
    }
}

__global__ void k_edge_agg2_fb(const int* __restrict__ src, const int* __restrict__ dst,
                               const float* __restrict__ w, const float* __restrict__ dinv,
                               const float* __restrict__ hp, float* __restrict__ agg2) {
    int gid = blockIdx.x * blockDim.x + threadIdx.x;
    int T = gridDim.x * blockDim.x;
    for (int e = gid; e < NE; e += T) {
        int s = src[e], d = dst[e];
        float nrm = dinv[s] * w[e] * dinv[d];
        float2 h = *reinterpret_cast<const float2*>(hp + 2 * s);
        atomicAdd(&agg2[2 * d],     nrm * h.x);
        atomicAdd(&agg2[2 * d + 1], nrm * h.y);
    }
}

// ================= pool + finalize =================

__global__ void k_pool(const float* __restrict__ agg2, const int* __restrict__ batch,
                       float* __restrict__ pooled, float* __restrict__ cnt) {
    __shared__ float ls0[NG], ls1[NG], lc[NG];
    if (threadIdx.x < NG) { ls0[threadIdx.x] = 0.f; ls1[threadIdx.x] = 0.f; lc[threadIdx.x] = 0.f; }
    __syncthreads();
    int gid = blockIdx.x * blockDim.x + threadIdx.x;
    int T = gridDim.x * blockDim.x;
    int lane = threadIdx.x & 63;
    for (int n = gid; __any(n < NN); n += T) {
        bool valid = n < NN;
        int b = 0; float vx = 0.f, vy = 0.f;
        if (valid) {
            b = batch[n];
            float2 v = *reinterpret_cast<const float2*>(agg2 + 2 * n);
            vx = v.x; vy = v.y;
        }
        int b0 = __shfl(b, 0);
        bool uni = __all(valid ? (b == b0) : 1);
        if (uni) {
            float rc = valid ? 1.f : 0.f;
            for (int off = 32; off > 0; off >>= 1) {
                vx += __shfl_down(vx, off);
                vy += __shfl_down(vy, off);
                rc += __shfl_down(rc, off);
            }
            if (lane == 0) { atomicAdd(&ls0[b0], vx); atomicAdd(&ls1[b0], vy); atomicAdd(&lc[b0], rc); }
        } else if (valid) {
            atomicAdd(&ls0[b], vx); atomicAdd(&ls1[b], vy); atomicAdd(&lc[b], 1.f);
        }
    }
    __syncthreads();
    if (threadIdx.x < NG) {
        int g = threadIdx.x;
        atomicAdd(&pooled[2 * g], ls0[g]);
        atomicAdd(&pooled[2 * g + 1], ls1[g]);
        atomicAdd(&cnt[g], lc[g]);
    }
}

__global__ void k_final(const float* __restrict__ pooled, const float* __restrict__ cnt,
                        const float* __restrict__ b2, float* __restrict__ out) {
    int i = threadIdx.x;
    if (i < 2 * NG) {
        int g = i >> 1, k = i & 1;
        float cg = cnt[g];
        out[i] = pooled[i] / fmaxf(cg, 1.0f) + (cg > 0.f ? b2[k] : 0.f);
    }
}

extern "C" void kernel_launch(void* const* d_in, const int* in_sizes, int n_in,
                              void* d_out, int out_size, void* d_ws, size_t ws_size,
                              hipStream_t stream) {
    const float* x     = (const float*)d_in[0];
    const int*   ei    = (const int*)  d_in[1];
    const float* ew    = (const float*)d_in[2];
    const int*   batch = (const int*)  d_in[3];
    const float* W1    = (const float*)d_in[4];
    const float* gamma = (const float*)d_in[6];
    const float* beta  = (const float*)d_in[7];
    const float* W2    = (const float*)d_in[8];
    const float* b2    = (const float*)d_in[9];
    float* out = (float*)d_out;

    float* ws = (float*)d_ws;
    // persistent: 9*NN floats
    float* dinv   = ws;                 // [NN]
    float* g1     = ws + NN;            // [NN]
    float* agg1   = ws + 2 * NN;        // [NN]
    float* hp     = ws + 3 * NN;        // [2*NN]
    float* g2     = ws + 5 * NN;        // [2*NN]
    float* agg2   = ws + 7 * NN;        // [2*NN]
    float* scal   = ws + 9 * NN;        // [8]
    float* cbuf   = ws + 9 * NN + 8;    // [64]
    float* pooled = ws + 9 * NN + 80;   // [128]
    float* cnt    = ws + 9 * NN + 224;  // [64]   (ends 288)
    int*   cntmat   = (int*)(ws + 9 * NN + 288);           // [BB*RB] = 3328
    int*   startmat = (int*)(ws + 9 * NN + 288 + 3328);    // [BB*RB] = 3328
    int*   bmeta    = (int*)(ws + 9 * NN + 288 + 6656);    // [32]    (ends 6976)
    uint2* ebuf     = (uint2*)(ws + 9 * NN + 6976);        // [NE] uint2 = 32*NN floats
    float* partial  = ws + 41 * NN + 6976;                 // up to [32*NN]

    const int* srcp = ei;
    const int* dstp = ei + NE;

    size_t availF = ws_size / sizeof(float);
    size_t need_base = 41 * (size_t)NN + 6976;
    size_t pf = (availF > need_base) ? (availF - need_base) : 0;

    const int NB = (NN + TPB - 1) / TPB;

    int Cs = (int)(pf / NN);        if (Cs > CSMAX) Cs = CSMAX;
    int C2 = (int)(pf / (2 * NN));  if (C2 > C2MAX) C2 = C2MAX;

    if (C2 >= 4) {
        // ---- bucketed gather path ----
        k_count  <<<BB, 1024, 0, stream>>>(dstp, cntmat);
        k_scan   <<<1, 832, 0, stream>>>(cntmat, startmat, bmeta);
        k_scatter<<<BB, 1024, 0, stream>>>(srcp, dstp, ew, startmat, ebuf);

        kB_deg     <<<RB * Cs, 1024, 0, stream>>>(ebuf, bmeta, partial, Cs);
        k_reduce_deg<<<NB, TPB, 0, stream>>>(partial, x, dinv, g1, scal, Cs);
        kB_t1      <<<RB * Cs, 1024, 0, stream>>>(ebuf, bmeta, g1, partial, Cs);
        k_reduce_t1<<<NB, TPB, 0, stream>>>(partial, dinv, g1, agg1, scal, Cs);
        k_prep     <<<1, 64, 0, stream>>>(scal, W1, gamma, cbuf, pooled, cnt);
        k_node_hp  <<<NB, TPB, 0, stream>>>(agg1, dinv, cbuf, beta, W2, scal, hp, g2);
        kB_t2      <<<RB * C2, 1024, 0, stream>>>(ebuf, bmeta, g2, partial, C2);
        k_reduce_t2<<<NB, TPB, 0, stream>>>(partial, dinv, g2, agg2, C2);
    } else {
        // ---- fallback atomic path (tiny scratch) ----
        const int ebl = 2048;
        hipMemsetAsync(dinv, 0, NN * sizeof(float), stream);
        k_edge_deg_fb <<<ebl, TPB, 0, stream>>>(dstp, ew, dinv);
        k_node_dinv_fb<<<NB, TPB, 0, stream>>>(x, dinv, agg1, scal);
        k_edge_agg1_fb<<<ebl, TPB, 0, stream>>>(srcp, dstp, ew, dinv, x, agg1);
        k_reduce_fb   <<<256, TPB, 0, stream>>>(agg1, scal);
        k_prep        <<<1, 64, 0, stream>>>(scal, W1, gamma, cbuf, pooled, cnt);
        k_node_hp_fb  <<<NB, TPB, 0, stream>>>(agg1, dinv, cbuf, beta, W2, scal, hp, agg2);
        k_edge_agg2_fb<<<ebl, TPB, 0, stream>>>(srcp, dstp, ew, dinv, hp, agg2);
    }

    k_pool <<<128, TPB, 0, stream>>>(agg2, batch, pooled, cnt);
    k_final<<<1, 128, 0, stream>>>(pooled, cnt, b2, out);
}